// Round 1
// baseline (431.915 us; speedup 1.0000x reference)
//
#include <hip/hip_runtime.h>
#include <math.h>

#define NN 512
#define CS 384
#define CZ 128
#define CH 16
#define HH 12
#define PQ 4
#define PV 8
#define LGS_S 516

typedef float f32x4 __attribute__((ext_vector_type(4)));
typedef __bf16 bf16x8 __attribute__((ext_vector_type(8)));
typedef __bf16 bf16x4 __attribute__((ext_vector_type(4)));

// ---------------- K0: repack weights into Wcat[384][1152] + bcat[1152] ----------------
__global__ void k_repack(const float* __restrict__ Wq,  const float* __restrict__ bq,
                         const float* __restrict__ Wkv, const float* __restrict__ bkv,
                         const float* __restrict__ Wqp, const float* __restrict__ bqp,
                         const float* __restrict__ Wkvp,const float* __restrict__ bkvp,
                         float* __restrict__ Wcat, float* __restrict__ bcat)
{
    const int total = CS * 1152;
    for (int idx = blockIdx.x * blockDim.x + threadIdx.x; idx < total; idx += gridDim.x * blockDim.x) {
        int kk = idx / 1152, n = idx % 1152;
        float vv;
        if (n < 192)      vv = Wq  [kk * 192 + n];
        else if (n < 576) vv = Wkv [kk * 384 + (n - 192)];
        else if (n < 720) vv = Wqp [kk * 144 + (n - 576)];
        else              vv = Wkvp[kk * 432 + (n - 720)];
        Wcat[idx] = vv;
    }
    int n = blockIdx.x * blockDim.x + threadIdx.x;
    if (n < 1152) {
        float vv;
        if (n < 192)      vv = bq  [n];
        else if (n < 576) vv = bkv [n - 192];
        else if (n < 720) vv = bqp [n - 576];
        else              vv = bkvp[n - 720];
        bcat[n] = vv;
    }
}

// ---------------- K1: s @ Wcat — tiled GEMM; k written TRANSPOSED (j fastest) --------
__global__ void k_proj(const float* __restrict__ s, const float* __restrict__ Wcat,
                       const float* __restrict__ bcat,
                       float* __restrict__ q, float* __restrict__ k_t, float* __restrict__ v,
                       float* __restrict__ qp_raw, float* __restrict__ kvp_raw)
{
    __shared__ float As[64 * 68];
    __shared__ float Bs[64 * 64];

    int tx = threadIdx.x & 15;
    int ty = threadIdx.x >> 4;
    int n0 = blockIdx.x * 64;
    int m0 = blockIdx.y * 64;

    float acc[4][4];
    #pragma unroll
    for (int r = 0; r < 4; ++r)
        #pragma unroll
        for (int cc = 0; cc < 4; ++cc) acc[r][cc] = 0.f;

    for (int kb = 0; kb < CS; kb += 64) {
        #pragma unroll
        for (int e = 0; e < 16; ++e) {
            int idx = e * 256 + threadIdx.x;
            int m = idx >> 6, kk = idx & 63;
            As[m * 68 + kk] = s[(size_t)(m0 + m) * CS + kb + kk];
        }
        #pragma unroll
        for (int e = 0; e < 16; ++e) {
            int idx = e * 256 + threadIdx.x;
            int kk = idx >> 6, n = idx & 63;
            Bs[kk * 64 + n] = Wcat[(size_t)(kb + kk) * 1152 + n0 + n];
        }
        __syncthreads();

        for (int kk = 0; kk < 64; kk += 4) {
            f32x4 a[4], b[4];
            #pragma unroll
            for (int r = 0; r < 4; ++r)
                a[r] = *(const f32x4*)&As[(ty * 4 + r) * 68 + kk];
            #pragma unroll
            for (int kq = 0; kq < 4; ++kq)
                b[kq] = *(const f32x4*)&Bs[(kk + kq) * 64 + tx * 4];
            #pragma unroll
            for (int kq = 0; kq < 4; ++kq)
                #pragma unroll
                for (int r = 0; r < 4; ++r)
                    #pragma unroll
                    for (int cc = 0; cc < 4; ++cc)
                        acc[r][cc] += a[r][kq] * b[kq][cc];
        }
        __syncthreads();
    }

    #pragma unroll
    for (int r = 0; r < 4; ++r) {
        int i = m0 + ty * 4 + r;
        #pragma unroll
        for (int cc = 0; cc < 4; ++cc) {
            int col = n0 + tx * 4 + cc;
            float val = acc[r][cc] + bcat[col];
            if (col < 192) {
                q[i * 192 + col] = val;
            } else if (col < 576) {
                int lc = col - 192;
                int h = lc / 32, w = lc % 32;
                if (w < CH) k_t[(h * CH + w) * NN + i] = val;   // transposed
                else        v[(i * HH + h) * CH + (w - CH)] = val;
            } else if (col < 720) {
                qp_raw[i * 144 + (col - 576)] = val;
            } else {
                kvp_raw[i * 432 + (col - 720)] = val;
            }
        }
    }
}

// ---------------- K2: rotate+translate; k_pts written TRANSPOSED (j fastest) ---------
__global__ void k_pts_transform(const float* __restrict__ qp_raw, const float* __restrict__ kvp_raw,
                                const float* __restrict__ rot, const float* __restrict__ trans,
                                float* __restrict__ q_pts, float* __restrict__ k_pts_t,
                                float* __restrict__ v_pts)
{
    int idx = blockIdx.x * blockDim.x + threadIdx.x;
    const int total = NN * HH * 16;
    if (idx >= total) return;
    int i = idx / (HH * 16);
    int r = idx % (HH * 16);
    int h = r / 16;
    int p = r % 16;

    float R[9], t3[3];
    for (int a = 0; a < 9; ++a) R[a] = rot[i * 9 + a];
    for (int a = 0; a < 3; ++a) t3[a] = trans[i * 3 + a];

    float x, y, zc;
    if (p < PQ) {
        x  = qp_raw[i * 144 + 0 * 48 + h * PQ + p];
        y  = qp_raw[i * 144 + 1 * 48 + h * PQ + p];
        zc = qp_raw[i * 144 + 2 * 48 + h * PQ + p];
    } else {
        int pp = p - PQ;
        x  = kvp_raw[i * 432 + 0 * 144 + h * 12 + pp];
        y  = kvp_raw[i * 432 + 1 * 144 + h * 12 + pp];
        zc = kvp_raw[i * 432 + 2 * 144 + h * 12 + pp];
    }
    float ox = R[0] * x + R[1] * y + R[2] * zc + t3[0];
    float oy = R[3] * x + R[4] * y + R[5] * zc + t3[1];
    float oz = R[6] * x + R[7] * y + R[8] * zc + t3[2];

    if (p < PQ) {
        int o = ((i * HH + h) * PQ + p) * 3;
        q_pts[o] = ox; q_pts[o + 1] = oy; q_pts[o + 2] = oz;
    } else {
        int pp = p - PQ;
        if (pp < PQ) {
            int rb = (h * PQ + pp) * 3;
            k_pts_t[(size_t)(rb + 0) * NN + i] = ox;   // transposed
            k_pts_t[(size_t)(rb + 1) * NN + i] = oy;
            k_pts_t[(size_t)(rb + 2) * NN + i] = oz;
        } else {
            int o = ((i * HH + h) * PV + (pp - PQ)) * 3;
            v_pts[o] = ox; v_pts[o + 1] = oy; v_pts[o + 2] = oz;
        }
    }
}

// ---------------- helper: QK^T + point-distance logit rows ----------------
__device__ __forceinline__ void ipa_logits_rows(
    int hbeg, int hend, int j,
    const float* __restrict__ k_t, const float* __restrict__ k_pts_t,
    const float* q_lds, const float* qp_lds, const float* hw_lds, const float* bb_l,
    float sqm, float (*lgs)[LGS_S])
{
    const float qk_scale = 0.14433756729740643f;  // sqrt(1/48)
    const float b_scale  = 0.57735026918962576f;  // sqrt(1/3)
    for (int h = hbeg; h < hend; ++h) {
        float accq = 0.f;
        #pragma unroll
        for (int c = 0; c < CH; ++c)
            accq += q_lds[h * CH + c] * k_t[(size_t)(h * CH + c) * NN + j];
        float s2 = 0.f;
        #pragma unroll
        for (int p = 0; p < PQ; ++p) {
            int rb = (h * PQ + p) * 3;
            float dx = qp_lds[rb + 0] - k_pts_t[(size_t)(rb + 0) * NN + j];
            float dy = qp_lds[rb + 1] - k_pts_t[(size_t)(rb + 1) * NN + j];
            float dz = qp_lds[rb + 2] - k_pts_t[(size_t)(rb + 2) * NN + j];
            s2 += dx * dx + dy * dy + dz * dz;
        }
        lgs[h][j] = accq * qk_scale + b_scale * bb_l[h] - 0.5f * hw_lds[h] * s2 + sqm;
    }
}

// ---------------- K_ATTN: fused bias + logits + softmax + o/o_pt + o_pair ----------------
// One block per i. z[i,:,:] staged ONCE into LDS as swizzled bf16 (128 KB).
// Swizzle: element (j,c) lives at zl[j*CZ + (c ^ ((j&7)<<3))]  (breaks the 256B-row bank conflict)
__global__ void __launch_bounds__(512, 2)
k_attn(const float* __restrict__ z, const float* __restrict__ Wb,
       const float* __restrict__ bb,
       const float* __restrict__ q, const float* __restrict__ k_t,
       const float* __restrict__ q_pts, const float* __restrict__ k_pts_t,
       const float* __restrict__ head_weights, const float* __restrict__ mask,
       const float* __restrict__ v, const float* __restrict__ v_pts,
       const float* __restrict__ rot, const float* __restrict__ trans,
       float* __restrict__ cat)
{
    __shared__ __bf16 zl[NN * CZ];          // 131072 B
    __shared__ float lgs[HH][LGS_S];        // 24768 B
    __shared__ float q_lds[HH * CH];
    __shared__ float qp_lds[HH * PQ * 3];
    __shared__ float hw_lds[HH];
    __shared__ float bb_l[HH];
    __shared__ float opt_lds[HH * PV * 3];

    const int i = blockIdx.x;
    const int tid = threadIdx.x;
    const int lane = tid & 63;
    const int wave = tid >> 6;
    const float* zbase = z + (size_t)i * NN * CZ;

    // ---- stage chunk 0: issue 16 float4 loads (stay in flight during logits 0..5) ----
    f32x4 zr[16];
    #pragma unroll
    for (int e = 0; e < 16; ++e)
        zr[e] = *(const f32x4*)(zbase + ((e * 512 + tid) << 2));

    if (tid < HH * CH)     q_lds[tid]  = q[(size_t)i * HH * CH + tid];
    if (tid < HH * PQ * 3) qp_lds[tid] = q_pts[(size_t)i * HH * PQ * 3 + tid];
    if (tid < HH) {
        float x = head_weights[tid];
        hw_lds[tid] = log1pf(expf(x)) * 0.13608276348795434f;  // softplus * sqrt(1/54)
        bb_l[tid] = bb[tid];
    }
    // raw barrier: orders the LDS writes WITHOUT draining the z loads (vmcnt stays hot)
    asm volatile("s_waitcnt lgkmcnt(0)" ::: "memory");
    __builtin_amdgcn_s_barrier();

    const float sqm = 100000.0f * (mask[i] * mask[tid] - 1.0f);

    ipa_logits_rows(0, 6, tid, k_t, k_pts_t, q_lds, qp_lds, hw_lds, bb_l, sqm, lgs);

    // ---- convert+write chunk 0 (compiler inserts the vmcnt waits here) ----
    #pragma unroll
    for (int e = 0; e < 16; ++e) {
        int f = e * 512 + tid;
        int j = f >> 5;
        int c0 = (f & 31) << 2;
        bf16x4 w;
        w[0] = (__bf16)zr[e][0]; w[1] = (__bf16)zr[e][1];
        w[2] = (__bf16)zr[e][2]; w[3] = (__bf16)zr[e][3];
        *(bf16x4*)&zl[j * CZ + (c0 ^ ((j & 7) << 3))] = w;
    }
    // ---- issue chunk 1, hide under logits 6..11 ----
    #pragma unroll
    for (int e = 0; e < 16; ++e)
        zr[e] = *(const f32x4*)(zbase + (((e + 16) * 512 + tid) << 2));

    ipa_logits_rows(6, 12, tid, k_t, k_pts_t, q_lds, qp_lds, hw_lds, bb_l, sqm, lgs);

    #pragma unroll
    for (int e = 0; e < 16; ++e) {
        int f = (e + 16) * 512 + tid;
        int j = f >> 5;
        int c0 = (f & 31) << 2;
        bf16x4 w;
        w[0] = (__bf16)zr[e][0]; w[1] = (__bf16)zr[e][1];
        w[2] = (__bf16)zr[e][2]; w[3] = (__bf16)zr[e][3];
        *(bf16x4*)&zl[j * CZ + (c0 ^ ((j & 7) << 3))] = w;
    }
    __syncthreads();

    // ---- bias MFMA: lgs[h][j] += sqrt(1/3) * (z @ Wb)[j][h] ----
    {
        const float b_scale = 0.57735026918962576f;
        const int hcol = lane & 15;
        const int q8 = (lane >> 4) * 8;
        bf16x8 wbf[4];
        #pragma unroll
        for (int kc = 0; kc < 4; ++kc) {
            #pragma unroll
            for (int jj = 0; jj < 8; ++jj) {
                int c = kc * 32 + q8 + jj;
                float wv = (hcol < HH) ? Wb[c * HH + hcol] * b_scale : 0.0f;
                wbf[kc][jj] = (__bf16)wv;
            }
        }
        #pragma unroll
        for (int t = 0; t < 4; ++t) {
            int j0 = (wave * 4 + t) * 16;
            int jrow = j0 + (lane & 15);
            int swz = (jrow & 7) << 3;
            f32x4 acc = {0.f, 0.f, 0.f, 0.f};
            #pragma unroll
            for (int kc = 0; kc < 4; ++kc) {
                bf16x8 af = *(const bf16x8*)&zl[jrow * CZ + ((kc * 32 + q8) ^ swz)];
                acc = __builtin_amdgcn_mfma_f32_16x16x32_bf16(af, wbf[kc], acc, 0, 0, 0);
            }
            if (hcol < HH) {
                #pragma unroll
                for (int r = 0; r < 4; ++r) {
                    int j = j0 + (lane >> 4) * 4 + r;
                    lgs[hcol][j] += acc[r];
                }
            }
        }
    }
    __syncthreads();

    // ---- softmax: 8 waves, wave w handles rows w, w+8 ----
    for (int row = wave; row < HH; row += 8) {
        float vals[8];
        float m = -1e30f;
        #pragma unroll
        for (int u = 0; u < 8; ++u) { vals[u] = lgs[row][lane + u * 64]; m = fmaxf(m, vals[u]); }
        #pragma unroll
        for (int off = 32; off >= 1; off >>= 1) m = fmaxf(m, __shfl_xor(m, off));
        float ssum = 0.f;
        #pragma unroll
        for (int u = 0; u < 8; ++u) { vals[u] = expf(vals[u] - m); ssum += vals[u]; }
        #pragma unroll
        for (int off = 32; off >= 1; off >>= 1) ssum += __shfl_xor(ssum, off);
        float inv = 1.0f / ssum;
        #pragma unroll
        for (int u = 0; u < 8; ++u) lgs[row][lane + u * 64] = vals[u] * inv;
    }
    __syncthreads();

    // ---- o = a·v  and o_pt partials = a·v_pts (f32 VALU, a read from LDS) ----
    if (tid < 480) {
        float acc = 0.f;
        if (tid < 192) {
            const float* lr = lgs[tid >> 4];
            const float* vp = v + tid;
            #pragma unroll 4
            for (int j = 0; j < NN; ++j)
                acc += lr[j] * vp[(size_t)j * 192];
            cat[(size_t)i * 2112 + tid] = acc;
        } else {
            int r = tid - 192;
            const float* lr = lgs[r / 24];      // PV*3 = 24
            const float* vp = v_pts + r;
            #pragma unroll 4
            for (int j = 0; j < NN; ++j)
                acc += lr[j] * vp[(size_t)j * 288];
            opt_lds[r] = acc;
        }
    }

    // ---- o_pair: MFMA, A = a (cvt from lgs f32), B = z (swizzled LDS) ----
    {
        int cl = lane & 15;
        int q4 = lane >> 4;
        int ha = (cl < HH) ? cl : (HH - 1);   // clamp: rows 12..15 duplicate row 11, not stored
        int cb = wave * 16 + cl;
        f32x4 pacc = {0.f, 0.f, 0.f, 0.f};
        for (int ks = 0; ks < 16; ++ks) {
            int jb = ks * 32 + q4 * 8;
            f32x4 a0 = *(const f32x4*)&lgs[ha][jb];
            f32x4 a1 = *(const f32x4*)&lgs[ha][jb + 4];
            bf16x8 af;
            af[0] = (__bf16)a0[0]; af[1] = (__bf16)a0[1];
            af[2] = (__bf16)a0[2]; af[3] = (__bf16)a0[3];
            af[4] = (__bf16)a1[0]; af[5] = (__bf16)a1[1];
            af[6] = (__bf16)a1[2]; af[7] = (__bf16)a1[3];
            bf16x8 bf;
            #pragma unroll
            for (int jj = 0; jj < 8; ++jj)
                bf[jj] = zl[(jb + jj) * CZ + (cb ^ (jj << 3))];
            pacc = __builtin_amdgcn_mfma_f32_16x16x32_bf16(af, bf, pacc, 0, 0, 0);
        }
        float* crow = cat + (size_t)i * 2112 + 576;
        #pragma unroll
        for (int r = 0; r < 4; ++r) {
            int h = q4 * 4 + r;
            if (h < HH) crow[h * CZ + cb] = pacc[r];
        }
    }
    __syncthreads();

    // ---- inverse frame + norm ----
    if (tid < HH * PV) {
        int hp = tid;
        float R[9], t3[3];
        #pragma unroll
        for (int a2 = 0; a2 < 9; ++a2) R[a2] = rot[i * 9 + a2];
        #pragma unroll
        for (int a2 = 0; a2 < 3; ++a2) t3[a2] = trans[i * 3 + a2];
        float gx = opt_lds[hp * 3 + 0] - t3[0];
        float gy = opt_lds[hp * 3 + 1] - t3[1];
        float gz = opt_lds[hp * 3 + 2] - t3[2];
        float lx = R[0] * gx + R[3] * gy + R[6] * gz;
        float ly = R[1] * gx + R[4] * gy + R[7] * gz;
        float lz = R[2] * gx + R[5] * gy + R[8] * gz;
        float* crow = cat + (size_t)i * 2112;
        crow[192 + 0 * 96 + hp] = lx;
        crow[192 + 1 * 96 + hp] = ly;
        crow[192 + 2 * 96 + hp] = lz;
        crow[480 + hp] = sqrtf(lx * lx + ly * ly + lz * lz + 1e-8f);
    }
}

// ---------------- K7: out = cat @ Wout + bout — tiled split-K GEMM ----------------
__global__ void k_final(const float* __restrict__ cat, const float* __restrict__ Wout,
                        const float* __restrict__ bout, float* __restrict__ out)
{
    __shared__ float As[64 * 52];
    __shared__ float Bs[48 * 64];

    int tx = threadIdx.x & 15;
    int ty = threadIdx.x >> 4;
    int n0 = blockIdx.x * 64;
    int m0 = blockIdx.y * 64;
    int k0 = blockIdx.z * 528;

    float acc[4][4];
    #pragma unroll
    for (int r = 0; r < 4; ++r)
        #pragma unroll
        for (int cc = 0; cc < 4; ++cc) acc[r][cc] = 0.f;

    for (int stage = 0; stage < 11; ++stage) {
        int kb = k0 + stage * 48;
        #pragma unroll
        for (int e = 0; e < 12; ++e) {
            int idx = e * 256 + threadIdx.x;
            int m = idx / 48, kk = idx % 48;
            As[m * 52 + kk] = cat[(size_t)(m0 + m) * 2112 + kb + kk];
        }
        #pragma unroll
        for (int e = 0; e < 12; ++e) {
            int idx = e * 256 + threadIdx.x;
            int kk = idx >> 6, n = idx & 63;
            Bs[kk * 64 + n] = Wout[(size_t)(kb + kk) * 384 + n0 + n];
        }
        __syncthreads();

        for (int kk = 0; kk < 48; kk += 4) {
            f32x4 a[4], b[4];
            #pragma unroll
            for (int r = 0; r < 4; ++r)
                a[r] = *(const f32x4*)&As[(ty * 4 + r) * 52 + kk];
            #pragma unroll
            for (int kq = 0; kq < 4; ++kq)
                b[kq] = *(const f32x4*)&Bs[(kk + kq) * 64 + tx * 4];
            #pragma unroll
            for (int kq = 0; kq < 4; ++kq)
                #pragma unroll
                for (int r = 0; r < 4; ++r)
                    #pragma unroll
                    for (int cc = 0; cc < 4; ++cc)
                        acc[r][cc] += a[r][kq] * b[kq][cc];
        }
        __syncthreads();
    }

    bool add_bias = (blockIdx.z == 0);
    #pragma unroll
    for (int r = 0; r < 4; ++r) {
        int m = m0 + ty * 4 + r;
        #pragma unroll
        for (int cc = 0; cc < 4; ++cc) {
            int n = n0 + tx * 4 + cc;
            float val = acc[r][cc] + (add_bias ? bout[n] : 0.f);
            atomicAdd(&out[(size_t)m * 384 + n], val);
        }
    }
}

extern "C" void kernel_launch(void* const* d_in, const int* in_sizes, int n_in,
                              void* d_out, int out_size, void* d_ws, size_t ws_size,
                              hipStream_t stream)
{
    const float* s     = (const float*)d_in[0];
    const float* z     = (const float*)d_in[1];
    const float* rot   = (const float*)d_in[2];
    const float* trans = (const float*)d_in[3];
    const float* mask  = (const float*)d_in[4];
    const float* Wq    = (const float*)d_in[5];
    const float* bq    = (const float*)d_in[6];
    const float* Wkv   = (const float*)d_in[7];
    const float* bkv   = (const float*)d_in[8];
    const float* Wqp   = (const float*)d_in[9];
    const float* bqp   = (const float*)d_in[10];
    const float* Wkvp  = (const float*)d_in[11];
    const float* bkvp  = (const float*)d_in[12];
    const float* Wb    = (const float*)d_in[13];
    const float* bb    = (const float*)d_in[14];
    const float* hw    = (const float*)d_in[15];
    const float* Wout  = (const float*)d_in[16];
    const float* bout  = (const float*)d_in[17];
    float* out = (float*)d_out;

    float* ws = (float*)d_ws;
    float* q       = ws;             // 98304
    float* k_t     = ws + 98304;     // 98304 (transposed)
    float* v       = ws + 196608;    // 98304
    float* qp_raw  = ws + 294912;    // 73728
    float* kvp_raw = ws + 368640;    // 221184
    float* q_pts   = ws + 589824;    // 73728
    float* k_pts_t = ws + 663552;    // 73728 (transposed)
    float* v_pts   = ws + 737280;    // 147456
    float* cat     = ws + 884736;    // 1081344
    float* Wcat    = ws + 1966080;   // 442368
    float* bcat    = ws + 2408448;   // 1152

    hipMemsetAsync(out, 0, (size_t)NN * CS * sizeof(float), stream);

    hipLaunchKernelGGL(k_repack, dim3(512), dim3(256), 0, stream,
                       Wq, bq, Wkv, bkv, Wqp, bqp, Wkvp, bkvp, Wcat, bcat);
    hipLaunchKernelGGL(k_proj, dim3(18, 8), dim3(256), 0, stream,
                       s, Wcat, bcat, q, k_t, v, qp_raw, kvp_raw);
    hipLaunchKernelGGL(k_pts_transform, dim3(384), dim3(256), 0, stream,
                       qp_raw, kvp_raw, rot, trans, q_pts, k_pts_t, v_pts);
    hipLaunchKernelGGL(k_attn, dim3(NN), dim3(512), 0, stream,
                       z, Wb, bb, q, k_t, q_pts, k_pts_t, hw, mask,
                       v, v_pts, rot, trans, cat);
    hipLaunchKernelGGL(k_final, dim3(6, 8, 4), dim3(256), 0, stream, cat, Wout, bout, out);
}

// Round 2
// 349.400 us; speedup vs baseline: 1.2362x; 1.2362x over previous
//
#include <hip/hip_runtime.h>
#include <math.h>

#define NN 512
#define CS 384
#define CZ 128
#define CH 16
#define HH 12
#define PQ 4
#define PV 8
#define LGS_S 516

typedef float f32x4 __attribute__((ext_vector_type(4)));
typedef __bf16 bf16x8 __attribute__((ext_vector_type(8)));

// ---------------- K0: repack weights into Wcat[384][1152] + bcat[1152] ----------------
__global__ void k_repack(const float* __restrict__ Wq,  const float* __restrict__ bq,
                         const float* __restrict__ Wkv, const float* __restrict__ bkv,
                         const float* __restrict__ Wqp, const float* __restrict__ bqp,
                         const float* __restrict__ Wkvp,const float* __restrict__ bkvp,
                         float* __restrict__ Wcat, float* __restrict__ bcat)
{
    const int total = CS * 1152;
    for (int idx = blockIdx.x * blockDim.x + threadIdx.x; idx < total; idx += gridDim.x * blockDim.x) {
        int kk = idx / 1152, n = idx % 1152;
        float vv;
        if (n < 192)      vv = Wq  [kk * 192 + n];
        else if (n < 576) vv = Wkv [kk * 384 + (n - 192)];
        else if (n < 720) vv = Wqp [kk * 144 + (n - 576)];
        else              vv = Wkvp[kk * 432 + (n - 720)];
        Wcat[idx] = vv;
    }
    int n = blockIdx.x * blockDim.x + threadIdx.x;
    if (n < 1152) {
        float vv;
        if (n < 192)      vv = bq  [n];
        else if (n < 576) vv = bkv [n - 192];
        else if (n < 720) vv = bqp [n - 576];
        else              vv = bkvp[n - 720];
        bcat[n] = vv;
    }
}

// ---------------- K1: s @ Wcat — BM=16 tiled GEMM; 576 blocks for occupancy --------
__global__ void k_proj(const float* __restrict__ s, const float* __restrict__ Wcat,
                       const float* __restrict__ bcat,
                       float* __restrict__ q, float* __restrict__ k_t, float* __restrict__ v,
                       float* __restrict__ qp_raw, float* __restrict__ kvp_raw)
{
    __shared__ float As[16 * 68];
    __shared__ float Bs[64 * 64];

    int tx = threadIdx.x & 15;
    int ty = threadIdx.x >> 4;      // 0..15 = output row within tile
    int n0 = blockIdx.x * 64;
    int m0 = blockIdx.y * 16;

    float acc[4] = {0.f, 0.f, 0.f, 0.f};

    for (int kb = 0; kb < CS; kb += 64) {
        #pragma unroll
        for (int e = 0; e < 4; ++e) {
            int idx = e * 256 + threadIdx.x;
            int m = idx >> 6, kk = idx & 63;
            As[m * 68 + kk] = s[(size_t)(m0 + m) * CS + kb + kk];
        }
        #pragma unroll
        for (int e = 0; e < 16; ++e) {
            int idx = e * 256 + threadIdx.x;
            int kk = idx >> 6, n = idx & 63;
            Bs[kk * 64 + n] = Wcat[(size_t)(kb + kk) * 1152 + n0 + n];
        }
        __syncthreads();

        for (int kk = 0; kk < 64; kk += 4) {
            f32x4 a = *(const f32x4*)&As[ty * 68 + kk];
            f32x4 b[4];
            #pragma unroll
            for (int kq = 0; kq < 4; ++kq)
                b[kq] = *(const f32x4*)&Bs[(kk + kq) * 64 + tx * 4];
            #pragma unroll
            for (int kq = 0; kq < 4; ++kq)
                #pragma unroll
                for (int cc = 0; cc < 4; ++cc)
                    acc[cc] += a[kq] * b[kq][cc];
        }
        __syncthreads();
    }

    int i = m0 + ty;
    #pragma unroll
    for (int cc = 0; cc < 4; ++cc) {
        int col = n0 + tx * 4 + cc;
        float val = acc[cc] + bcat[col];
        if (col < 192) {
            q[i * 192 + col] = val;
        } else if (col < 576) {
            int lc = col - 192;
            int h = lc / 32, w = lc % 32;
            if (w < CH) k_t[(h * CH + w) * NN + i] = val;   // transposed
            else        v[(i * HH + h) * CH + (w - CH)] = val;
        } else if (col < 720) {
            qp_raw[i * 144 + (col - 576)] = val;
        } else {
            kvp_raw[i * 432 + (col - 720)] = val;
        }
    }
}

// ---------------- K2: rotate+translate; k_pts written TRANSPOSED (j fastest) ---------
__global__ void k_pts_transform(const float* __restrict__ qp_raw, const float* __restrict__ kvp_raw,
                                const float* __restrict__ rot, const float* __restrict__ trans,
                                float* __restrict__ q_pts, float* __restrict__ k_pts_t,
                                float* __restrict__ v_pts)
{
    int idx = blockIdx.x * blockDim.x + threadIdx.x;
    const int total = NN * HH * 16;
    if (idx >= total) return;
    int i = idx / (HH * 16);
    int r = idx % (HH * 16);
    int h = r / 16;
    int p = r % 16;

    float R[9], t3[3];
    for (int a = 0; a < 9; ++a) R[a] = rot[i * 9 + a];
    for (int a = 0; a < 3; ++a) t3[a] = trans[i * 3 + a];

    float x, y, zc;
    if (p < PQ) {
        x  = qp_raw[i * 144 + 0 * 48 + h * PQ + p];
        y  = qp_raw[i * 144 + 1 * 48 + h * PQ + p];
        zc = qp_raw[i * 144 + 2 * 48 + h * PQ + p];
    } else {
        int pp = p - PQ;
        x  = kvp_raw[i * 432 + 0 * 144 + h * 12 + pp];
        y  = kvp_raw[i * 432 + 1 * 144 + h * 12 + pp];
        zc = kvp_raw[i * 432 + 2 * 144 + h * 12 + pp];
    }
    float ox = R[0] * x + R[1] * y + R[2] * zc + t3[0];
    float oy = R[3] * x + R[4] * y + R[5] * zc + t3[1];
    float oz = R[6] * x + R[7] * y + R[8] * zc + t3[2];

    if (p < PQ) {
        int o = ((i * HH + h) * PQ + p) * 3;
        q_pts[o] = ox; q_pts[o + 1] = oy; q_pts[o + 2] = oz;
    } else {
        int pp = p - PQ;
        if (pp < PQ) {
            int rb = (h * PQ + pp) * 3;
            k_pts_t[(size_t)(rb + 0) * NN + i] = ox;   // transposed
            k_pts_t[(size_t)(rb + 1) * NN + i] = oy;
            k_pts_t[(size_t)(rb + 2) * NN + i] = oz;
        } else {
            int o = ((i * HH + h) * PV + (pp - PQ)) * 3;
            v_pts[o] = ox; v_pts[o + 1] = oy; v_pts[o + 2] = oz;
        }
    }
}

// ---------------- K_ATTN: fused bias + logits + softmax + o/o_pt + o_pair ----------------
// One block per i. NO z LDS staging: z streamed from global for both MFMA phases.
// LDS ~26 KB -> 2 blocks/CU co-resident (16 waves/CU) -> latency hidden by TLP.
__global__ void __launch_bounds__(512, 4)
k_attn(const float* __restrict__ z, const float* __restrict__ Wb,
       const float* __restrict__ bb,
       const float* __restrict__ q, const float* __restrict__ k_t,
       const float* __restrict__ q_pts, const float* __restrict__ k_pts_t,
       const float* __restrict__ head_weights, const float* __restrict__ mask,
       const float* __restrict__ v, const float* __restrict__ v_pts,
       const float* __restrict__ rot, const float* __restrict__ trans,
       float* __restrict__ cat)
{
    __shared__ float lgs[HH][LGS_S];        // 24768 B
    __shared__ float q_lds[HH * CH];
    __shared__ float qp_lds[HH * PQ * 3];
    __shared__ float hw_lds[HH];
    __shared__ float bb_l[HH];
    __shared__ float opt_lds[HH * PV * 3];

    const int i = blockIdx.x;
    const int tid = threadIdx.x;
    const int lane = tid & 63;
    const int wave = tid >> 6;
    const float* zbase = z + (size_t)i * NN * CZ;

    // ---- stage small per-i state ----
    if (tid < HH * CH)     q_lds[tid]  = q[(size_t)i * HH * CH + tid];
    if (tid < HH * PQ * 3) qp_lds[tid] = q_pts[(size_t)i * HH * PQ * 3 + tid];
    if (tid < HH) {
        float x = head_weights[tid];
        hw_lds[tid] = log1pf(expf(x)) * 0.13608276348795434f;  // softplus * sqrt(1/54)
        bb_l[tid] = bb[tid];
    }

    // ---- Phase A: bias MFMA, z streamed from global, written into lgs ----
    // lgs[h][j] = b_scale * (z[i] @ Wb)[j][h]
    {
        const float b_scale = 0.57735026918962576f;
        const int hcol = lane & 15;
        const int q8 = (lane >> 4) * 8;
        bf16x8 wbf[4];
        #pragma unroll
        for (int kc = 0; kc < 4; ++kc) {
            #pragma unroll
            for (int jj = 0; jj < 8; ++jj) {
                int c = kc * 32 + q8 + jj;
                float wv = (hcol < HH) ? Wb[c * HH + hcol] * b_scale : 0.0f;
                wbf[kc][jj] = (__bf16)wv;
            }
        }
        #pragma unroll
        for (int t = 0; t < 4; ++t) {
            int j0 = (wave * 4 + t) * 16;
            const float* zrow = zbase + (size_t)(j0 + hcol) * CZ;
            f32x4 acc = {0.f, 0.f, 0.f, 0.f};
            #pragma unroll
            for (int kc = 0; kc < 4; ++kc) {
                float4 z0 = *(const float4*)(zrow + kc * 32 + q8);
                float4 z1 = *(const float4*)(zrow + kc * 32 + q8 + 4);
                bf16x8 afrag;
                afrag[0] = (__bf16)z0.x; afrag[1] = (__bf16)z0.y;
                afrag[2] = (__bf16)z0.z; afrag[3] = (__bf16)z0.w;
                afrag[4] = (__bf16)z1.x; afrag[5] = (__bf16)z1.y;
                afrag[6] = (__bf16)z1.z; afrag[7] = (__bf16)z1.w;
                acc = __builtin_amdgcn_mfma_f32_16x16x32_bf16(afrag, wbf[kc], acc, 0, 0, 0);
            }
            if (hcol < HH) {
                #pragma unroll
                for (int r = 0; r < 4; ++r) {
                    int j = j0 + (lane >> 4) * 4 + r;
                    lgs[hcol][j] = acc[r];
                }
            }
        }
    }
    __syncthreads();

    // ---- Phase B: logits += QK^T + point-dist + mask (thread tid owns column tid) ----
    {
        const float qk_scale = 0.14433756729740643f;  // sqrt(1/48)
        const float b_scale  = 0.57735026918962576f;  // sqrt(1/3)
        const float sqm = 100000.0f * (mask[i] * mask[tid] - 1.0f);
        #pragma unroll
        for (int h = 0; h < HH; ++h) {
            float accq = 0.f;
            #pragma unroll
            for (int c = 0; c < CH; ++c)
                accq += q_lds[h * CH + c] * k_t[(size_t)(h * CH + c) * NN + tid];
            float s2 = 0.f;
            #pragma unroll
            for (int p = 0; p < PQ; ++p) {
                int rb = (h * PQ + p) * 3;
                float dx = qp_lds[rb + 0] - k_pts_t[(size_t)(rb + 0) * NN + tid];
                float dy = qp_lds[rb + 1] - k_pts_t[(size_t)(rb + 1) * NN + tid];
                float dz = qp_lds[rb + 2] - k_pts_t[(size_t)(rb + 2) * NN + tid];
                s2 += dx * dx + dy * dy + dz * dz;
            }
            lgs[h][tid] += accq * qk_scale + b_scale * bb_l[h] - 0.5f * hw_lds[h] * s2 + sqm;
        }
    }
    __syncthreads();

    // ---- softmax: 8 waves, wave w handles rows w, w+8 ----
    for (int row = wave; row < HH; row += 8) {
        float vals[8];
        float m = -1e30f;
        #pragma unroll
        for (int u = 0; u < 8; ++u) { vals[u] = lgs[row][lane + u * 64]; m = fmaxf(m, vals[u]); }
        #pragma unroll
        for (int off = 32; off >= 1; off >>= 1) m = fmaxf(m, __shfl_xor(m, off));
        float ssum = 0.f;
        #pragma unroll
        for (int u = 0; u < 8; ++u) { vals[u] = expf(vals[u] - m); ssum += vals[u]; }
        #pragma unroll
        for (int off = 32; off >= 1; off >>= 1) ssum += __shfl_xor(ssum, off);
        float inv = 1.0f / ssum;
        #pragma unroll
        for (int u = 0; u < 8; ++u) lgs[row][lane + u * 64] = vals[u] * inv;
    }
    __syncthreads();

    // ---- o = a·v  and o_pt partials = a·v_pts (f32 VALU, a read from LDS) ----
    if (tid < 480) {
        float acc = 0.f;
        if (tid < 192) {
            const float* lr = lgs[tid >> 4];
            const float* vp = v + tid;
            #pragma unroll 4
            for (int j = 0; j < NN; ++j)
                acc += lr[j] * vp[(size_t)j * 192];
            cat[(size_t)i * 2112 + tid] = acc;
        } else {
            int r = tid - 192;
            const float* lr = lgs[r / 24];      // PV*3 = 24
            const float* vp = v_pts + r;
            #pragma unroll 4
            for (int j = 0; j < NN; ++j)
                acc += lr[j] * vp[(size_t)j * 288];
            opt_lds[r] = acc;
        }
    }

    // ---- o_pair: MFMA, A = a (cvt from lgs f32), B = z streamed from global ----
    {
        int cl = lane & 15;
        int q4 = lane >> 4;
        int ha = (cl < HH) ? cl : (HH - 1);   // clamp: rows 12..15 duplicate row 11, not stored
        int cb = wave * 16 + cl;
        f32x4 pacc = {0.f, 0.f, 0.f, 0.f};
        for (int ks = 0; ks < 16; ++ks) {
            int jb = ks * 32 + q4 * 8;
            f32x4 a0 = *(const f32x4*)&lgs[ha][jb];
            f32x4 a1 = *(const f32x4*)&lgs[ha][jb + 4];
            bf16x8 af;
            af[0] = (__bf16)a0[0]; af[1] = (__bf16)a0[1];
            af[2] = (__bf16)a0[2]; af[3] = (__bf16)a0[3];
            af[4] = (__bf16)a1[0]; af[5] = (__bf16)a1[1];
            af[6] = (__bf16)a1[2]; af[7] = (__bf16)a1[3];
            bf16x8 bf;
            #pragma unroll
            for (int jj = 0; jj < 8; ++jj)
                bf[jj] = (__bf16)zbase[(size_t)(jb + jj) * CZ + cb];
            pacc = __builtin_amdgcn_mfma_f32_16x16x32_bf16(af, bf, pacc, 0, 0, 0);
        }
        float* crow = cat + (size_t)i * 2112 + 576;
        #pragma unroll
        for (int r = 0; r < 4; ++r) {
            int h = q4 * 4 + r;
            if (h < HH) crow[h * CZ + cb] = pacc[r];
        }
    }
    __syncthreads();

    // ---- inverse frame + norm ----
    if (tid < HH * PV) {
        int hp = tid;
        float R[9], t3[3];
        #pragma unroll
        for (int a2 = 0; a2 < 9; ++a2) R[a2] = rot[i * 9 + a2];
        #pragma unroll
        for (int a2 = 0; a2 < 3; ++a2) t3[a2] = trans[i * 3 + a2];
        float gx = opt_lds[hp * 3 + 0] - t3[0];
        float gy = opt_lds[hp * 3 + 1] - t3[1];
        float gz = opt_lds[hp * 3 + 2] - t3[2];
        float lx = R[0] * gx + R[3] * gy + R[6] * gz;
        float ly = R[1] * gx + R[4] * gy + R[7] * gz;
        float lz = R[2] * gx + R[5] * gy + R[8] * gz;
        float* crow = cat + (size_t)i * 2112;
        crow[192 + 0 * 96 + hp] = lx;
        crow[192 + 1 * 96 + hp] = ly;
        crow[192 + 2 * 96 + hp] = lz;
        crow[480 + hp] = sqrtf(lx * lx + ly * ly + lz * lz + 1e-8f);
    }
}

// ---------------- K7: out = cat @ Wout + bout — BM=16 split-K GEMM; 768 blocks ----------------
__global__ void k_final(const float* __restrict__ cat, const float* __restrict__ Wout,
                        const float* __restrict__ bout, float* __restrict__ out)
{
    __shared__ float As[16 * 52];
    __shared__ float Bs[48 * 64];

    int tx = threadIdx.x & 15;
    int ty = threadIdx.x >> 4;      // 0..15 = output row within tile
    int n0 = blockIdx.x * 64;
    int m0 = blockIdx.y * 16;
    int k0 = blockIdx.z * 528;

    float acc[4] = {0.f, 0.f, 0.f, 0.f};

    for (int stage = 0; stage < 11; ++stage) {
        int kb = k0 + stage * 48;
        #pragma unroll
        for (int e = 0; e < 3; ++e) {
            int idx = e * 256 + threadIdx.x;
            int m = idx / 48, kk = idx % 48;
            As[m * 52 + kk] = cat[(size_t)(m0 + m) * 2112 + kb + kk];
        }
        #pragma unroll
        for (int e = 0; e < 12; ++e) {
            int idx = e * 256 + threadIdx.x;
            int kk = idx >> 6, n = idx & 63;
            Bs[kk * 64 + n] = Wout[(size_t)(kb + kk) * 384 + n0 + n];
        }
        __syncthreads();

        for (int kk = 0; kk < 48; kk += 4) {
            f32x4 a = *(const f32x4*)&As[ty * 52 + kk];
            f32x4 b[4];
            #pragma unroll
            for (int kq = 0; kq < 4; ++kq)
                b[kq] = *(const f32x4*)&Bs[(kk + kq) * 64 + tx * 4];
            #pragma unroll
            for (int kq = 0; kq < 4; ++kq)
                #pragma unroll
                for (int cc = 0; cc < 4; ++cc)
                    acc[cc] += a[kq] * b[kq][cc];
        }
        __syncthreads();
    }

    bool add_bias = (blockIdx.z == 0);
    int m = m0 + ty;
    #pragma unroll
    for (int cc = 0; cc < 4; ++cc) {
        int n = n0 + tx * 4 + cc;
        float val = acc[cc] + (add_bias ? bout[n] : 0.f);
        atomicAdd(&out[(size_t)m * 384 + n], val);
    }
}

extern "C" void kernel_launch(void* const* d_in, const int* in_sizes, int n_in,
                              void* d_out, int out_size, void* d_ws, size_t ws_size,
                              hipStream_t stream)
{
    const float* s     = (const float*)d_in[0];
    const float* z     = (const float*)d_in[1];
    const float* rot   = (const float*)d_in[2];
    const float* trans = (const float*)d_in[3];
    const float* mask  = (const float*)d_in[4];
    const float* Wq    = (const float*)d_in[5];
    const float* bq    = (const float*)d_in[6];
    const float* Wkv   = (const float*)d_in[7];
    const float* bkv   = (const float*)d_in[8];
    const float* Wqp   = (const float*)d_in[9];
    const float* bqp   = (const float*)d_in[10];
    const float* Wkvp  = (const float*)d_in[11];
    const float* bkvp  = (const float*)d_in[12];
    const float* Wb    = (const float*)d_in[13];
    const float* bb    = (const float*)d_in[14];
    const float* hw    = (const float*)d_in[15];
    const float* Wout  = (const float*)d_in[16];
    const float* bout  = (const float*)d_in[17];
    float* out = (float*)d_out;

    float* ws = (float*)d_ws;
    float* q       = ws;             // 98304
    float* k_t     = ws + 98304;     // 98304 (transposed)
    float* v       = ws + 196608;    // 98304
    float* qp_raw  = ws + 294912;    // 73728
    float* kvp_raw = ws + 368640;    // 221184
    float* q_pts   = ws + 589824;    // 73728
    float* k_pts_t = ws + 663552;    // 73728 (transposed)
    float* v_pts   = ws + 737280;    // 147456
    float* cat     = ws + 884736;    // 1081344
    float* Wcat    = ws + 1966080;   // 442368
    float* bcat    = ws + 2408448;   // 1152

    hipMemsetAsync(out, 0, (size_t)NN * CS * sizeof(float), stream);

    hipLaunchKernelGGL(k_repack, dim3(512), dim3(256), 0, stream,
                       Wq, bq, Wkv, bkv, Wqp, bqp, Wkvp, bkvp, Wcat, bcat);
    hipLaunchKernelGGL(k_proj, dim3(18, 32), dim3(256), 0, stream,
                       s, Wcat, bcat, q, k_t, v, qp_raw, kvp_raw);
    hipLaunchKernelGGL(k_pts_transform, dim3(384), dim3(256), 0, stream,
                       qp_raw, kvp_raw, rot, trans, q_pts, k_pts_t, v_pts);
    hipLaunchKernelGGL(k_attn, dim3(NN), dim3(512), 0, stream,
                       z, Wb, bb, q, k_t, q_pts, k_pts_t, hw, mask,
                       v, v_pts, rot, trans, cat);
    hipLaunchKernelGGL(k_final, dim3(6, 32, 4), dim3(256), 0, stream, cat, Wout, bout, out);
}